// Round 11
// baseline (165.671 us; speedup 1.0000x reference)
//
#include <hip/hip_runtime.h>
#include <hip/hip_bf16.h>
#include <stdint.h>

#define B_   8
#define DIM  1024
#define T_   2048
#define H_   16
#define HD   64

typedef __attribute__((ext_vector_type(8))) short bf16x8;
typedef __attribute__((ext_vector_type(4))) float f32x4;
typedef __attribute__((ext_vector_type(4))) unsigned short u16x4;

__device__ __forceinline__ unsigned short f2bf(float f) {
    union { float f; unsigned u; } v{f};
    unsigned r = v.u + 0x7fffu + ((v.u >> 16) & 1u);   // RNE
    return (unsigned short)(r >> 16);
}

// async 16B/lane global->LDS; lds dest must be wave-uniform base (HW adds lane*16)
__device__ __forceinline__ void gl_lds16(const unsigned short* g, unsigned short* l) {
    __builtin_amdgcn_global_load_lds(
        (const __attribute__((address_space(1))) void*)(const void*)g,
        (__attribute__((address_space(3))) void*)(void*)l,
        16, 0, 0);
}

// Read one 16B MFMA fragment from a swizzled [rows][64] bf16 LDS tile.
// Physical 16B-block = logical_colgroup ^ (row&7).
__device__ __forceinline__ bf16x8 ld_frag(const unsigned short* smem, int row, int cg) {
    return *reinterpret_cast<const bf16x8*>(smem + row * 64 + (((cg) ^ (row & 7)) << 3));
}

// ---------------------------------------------------------------------------
// Kernel 1: x (B,DIM,T) f32  ->  XT (B,T,DIM) bf16   (transpose + cast)
// ---------------------------------------------------------------------------
__global__ void xpose_cast(const float* __restrict__ x, unsigned short* __restrict__ xt) {
    __shared__ float tile[64][65];
    const int b = blockIdx.z;
    const int d0 = blockIdx.y * 64, t0 = blockIdx.x * 64;
    const int tid = threadIdx.x;
    const int c = tid & 63;
    const int r0 = tid >> 6;

    const float* xp = x + ((size_t)b * DIM + d0) * T_ + t0;
#pragma unroll
    for (int i = 0; i < 16; ++i) {
        int r = r0 + i * 4;                       // d offset
        tile[r][c] = xp[(size_t)r * T_ + c];
    }
    __syncthreads();
    unsigned short* op = xt + ((size_t)b * T_ + t0) * DIM + d0;
    const int ci = (tid & 15) * 4;                // d offset (4-wide)
    const int rr = tid >> 4;                      // t offset base 0..15
#pragma unroll
    for (int i = 0; i < 4; ++i) {
        int r = rr + i * 16;                      // t offset
        u16x4 v;
#pragma unroll
        for (int j = 0; j < 4; ++j) v[j] = f2bf(tile[ci + j][r]);
        *reinterpret_cast<u16x4*>(op + (size_t)r * DIM + ci) = v;
    }
}

// ---------------------------------------------------------------------------
// Kernel 2: build diagonal M-tiles in MFMA *fragment* layout (f32 src):
// Mf[h][dg][cg][row][j] = w[h][ 64*(dg-1) + row - (cg*8+j) ]  (0 if lag<0)
// ---------------------------------------------------------------------------
__global__ void gen_mfrag(const float* __restrict__ tw, unsigned short* __restrict__ Mf) {
    const int h = blockIdx.y, dg = blockIdx.x;
    const int D = (dg - 1) * 64;
    const float* twh = tw + h * T_;
    unsigned short* out = Mf + (((size_t)h * 32 + dg) << 13);   // 8192 elems per (h,dg)
    for (int v = threadIdx.x; v < 1024; v += 256) {
        int cg = v >> 7, row = v & 127;
        bf16x8 w;
#pragma unroll
        for (int j = 0; j < 8; ++j) {
            int lag = D + row - (cg * 8 + j);
            w[j] = (lag >= 0) ? (short)f2bf(twh[lag]) : (short)0;
        }
        *reinterpret_cast<bf16x8*>(out + (size_t)v * 8) = w;
    }
}

// ---------------------------------------------------------------------------
// Kernel 3: rearrange a (DIM,DIM) f32 weight into bf16 MFMA fragment layout:
// Wf[slab][kt][cg][row][j] = W[slab*128+row][kt*64 + cg*8 + j]
//   slab in [0,8), kt in [0,16), cg in [0,8), row in [0,128). 2 MiB, L2-hot.
// ---------------------------------------------------------------------------
__global__ void gen_wfrag(const float* __restrict__ W, unsigned short* __restrict__ Wf) {
    const int kt = blockIdx.x, my = blockIdx.y;
    unsigned short* out = Wf + (((size_t)my * 16 + kt) << 13);
    for (int v = threadIdx.x; v < 1024; v += 256) {
        int cg = v >> 7, row = v & 127;
        const float* src = W + (size_t)(my * 128 + row) * DIM + kt * 64 + cg * 8;
        bf16x8 w;
#pragma unroll
        for (int j = 0; j < 8; ++j) w[j] = (short)f2bf(src[j]);
        *reinterpret_cast<bf16x8*>(out + (size_t)v * 8) = w;
    }
}

// ---------------------------------------------------------------------------
// GEMM v4: wave tile 128x64 (acc[8][4]), block 256M x 128N, 4 waves (2wr x 2wc).
// A-fragments DIRECT FROM L2 (fragment-layout Wf; VMEM pipe, L1-shared across
// the wc pair) -> LDS pipe carries only B (8 ds_read_b128 per wave-K-tile vs
// 64 MFMA: matrix-bound). B ring-2 dbuf, conv4's proven single-syncthreads
// discipline; prefetch lead = one full K-tile body (~1200cyc) >> L2 latency.
// Grid 512, chunked XCD swizzle (each XCD owns one batch).
// ---------------------------------------------------------------------------
template <bool OUT_BF16>
__global__ __launch_bounds__(256, 2)
void gemm4_k(const unsigned short* __restrict__ Wf,   // (8,16,8,128,8) bf16
             const unsigned short* __restrict__ Bm,   // (B,T,DIM) bf16
             const float* __restrict__ bias,          // (DIM) f32
             void* __restrict__ Out) {
    __shared__ __align__(16) unsigned short Bs[2][128 * 64];

    const int flat = blockIdx.x;                 // 512 blocks
    const int wid  = (flat & 7) * 64 + (flat >> 3);
    const int nx   = wid & 15;                   // N tile (128)
    const int mb   = (wid >> 4) & 3;             // M tile (256)
    const int b    = wid >> 6;                   // batch

    const int tid = threadIdx.x, lane = tid & 63, wv = tid >> 6;
    const int wr = wv >> 1, wc = wv & 1;
    const int n0 = nx * 128;
    const unsigned short* Bb  = Bm + (size_t)b * T_ * DIM + (size_t)n0 * DIM;
    const unsigned short* Awr = Wf + (((size_t)(mb * 2 + wr) * 16) << 13);

    const int lrow = lane & 15, lg = lane >> 4;
    const int rsub = lane >> 3;
    const int g = (lane & 7) ^ rsub;

    // lane-constant part of the A-fragment elem offset: (cg=lg, row=mt*16+lrow)
    const int aoff = (lg * 128 + lrow) * 8;

    f32x4 acc[8][4] = {};

    auto BSTAGE = [&](int kt, int p) {
        const int k0 = kt * 64;
#pragma unroll
        for (int it = 0; it < 4; ++it) {
            int ch = wv * 4 + it;                 // 16 chunks of 8 rows
            int r  = ch * 8 + rsub;
            gl_lds16(Bb + (size_t)r * DIM + k0 + g * 8, &Bs[p][0] + ch * 512);
        }
    };

    BSTAGE(0, 0);
    __syncthreads();

    const int NT = DIM / 64;                     // 16
    for (int kt = 0; kt < NT; ++kt) {
        const int cur = kt & 1;
        if (kt + 1 < NT) BSTAGE(kt + 1, cur ^ 1);   // loads fly over this K-tile

        const unsigned short* At = Awr + ((size_t)kt << 13);
        const unsigned short* Pb = &Bs[cur][0];

        // kk = 0
        {
            bf16x8 af[8], bfr[4];
#pragma unroll
            for (int mt = 0; mt < 8; ++mt)
                af[mt] = *reinterpret_cast<const bf16x8*>(At + aoff + mt * 128);
#pragma unroll
            for (int nt = 0; nt < 4; ++nt) bfr[nt] = ld_frag(Pb, wc * 64 + nt * 16 + lrow, lg);
#pragma unroll
            for (int mt = 0; mt < 8; ++mt)
#pragma unroll
                for (int nt = 0; nt < 4; ++nt)
                    acc[mt][nt] = __builtin_amdgcn_mfma_f32_16x16x32_bf16(af[mt], bfr[nt], acc[mt][nt], 0, 0, 0);
        }
        // kk = 1
        {
            bf16x8 af[8], bfr[4];
#pragma unroll
            for (int mt = 0; mt < 8; ++mt)
                af[mt] = *reinterpret_cast<const bf16x8*>(At + 4096 + aoff + mt * 128);
#pragma unroll
            for (int nt = 0; nt < 4; ++nt) bfr[nt] = ld_frag(Pb, wc * 64 + nt * 16 + lrow, 4 + lg);
#pragma unroll
            for (int mt = 0; mt < 8; ++mt)
#pragma unroll
                for (int nt = 0; nt < 4; ++nt)
                    acc[mt][nt] = __builtin_amdgcn_mfma_f32_16x16x32_bf16(af[mt], bfr[nt], acc[mt][nt], 0, 0, 0);
        }

        __syncthreads();                         // stage landed + reads of buf cur done
    }

    const size_t ob = (size_t)b * DIM * T_;
#pragma unroll
    for (int mt = 0; mt < 8; ++mt) {
        int d = mb * 256 + wr * 128 + mt * 16 + lg * 4;
#pragma unroll
        for (int nt = 0; nt < 4; ++nt) {
            int t = n0 + wc * 64 + nt * 16 + lrow;
#pragma unroll
            for (int r = 0; r < 4; ++r) {
                float v = acc[mt][nt][r] + bias[d + r];
                if constexpr (OUT_BF16)
                    ((unsigned short*)Out)[ob + (size_t)(d + r) * T_ + t] = f2bf(v);
                else
                    ((float*)Out)[ob + (size_t)(d + r) * T_ + t] = v;
            }
        }
    }
}

// ---------------------------------------------------------------------------
// Conv v4 (proven): balanced triangular GEMM, A-fragments direct from L2,
// double-buffered P, ONE barrier per K-step, h-major XCD chunk.
// ---------------------------------------------------------------------------
__global__ void conv4_k(const unsigned short* __restrict__ H1,   // (B,DIM,T) bf16
                        const unsigned short* __restrict__ Mf,   // (H,32,8,128,8) bf16
                        const float* __restrict__ tb,            // (H,T) f32
                        unsigned short* __restrict__ Cb) {       // (B,T,DIM) bf16
    __shared__ __align__(16) unsigned short Ps[2][64 * 64];

    const int flat = blockIdx.x;                 // 1024 blocks
    const int wid  = (flat & 7) * 128 + (flat >> 3);
    const int bx   = wid & 7;
    const int b    = (wid >> 3) & 7;
    const int h    = wid >> 6;

    const int tid = threadIdx.x, lane = tid & 63, wv = tid >> 6;
    const unsigned short* Hb = H1 + ((size_t)b * DIM + h * HD) * T_;
    const unsigned short* Ah = Mf + ((size_t)h * 32) * 8192;

    const int lrow = lane & 15, lg = lane >> 4;
    const int rsub = lane >> 3;
    const int g = (lane & 7) ^ rsub;

    // lane-constant part of the A-fragment offset (elems)
    const int aoff = (lg * 128 + wv * 32 + lrow) * 8;

#pragma unroll
    for (int ph = 0; ph < 2; ++ph) {
        const int ut = ph ? bx : (T_ / 128 - 1 - bx);
        const int u0 = ut * 128;
        const int nk = 2 * ut + 2;
        f32x4 acc[2][4] = {};

        // prologue: stage P(kt=0) into buf 0
#pragma unroll
        for (int it = 0; it < 2; ++it) {
            int ch = wv * 2 + it;
            int r  = ch * 8 + rsub;
            gl_lds16(Hb + (size_t)r * T_ + g * 8, &Ps[0][0] + ch * 512);
        }
        __syncthreads();

        for (int kt = 0; kt < nk; ++kt) {
            const int cur = kt & 1;
            // stage next P tile into the other buffer (issued before compute)
            if (kt + 1 < nk) {
                const int t0n = (kt + 1) * 64;
#pragma unroll
                for (int it = 0; it < 2; ++it) {
                    int ch = wv * 2 + it;
                    int r  = ch * 8 + rsub;
                    gl_lds16(Hb + (size_t)r * T_ + t0n + g * 8, &Ps[cur ^ 1][0] + ch * 512);
                }
            }
            // A fragments straight from L2 (fragment-layout Mf)
            const int dg = 2 * ut - kt + 1;
            const unsigned short* At = Ah + (size_t)dg * 8192;
            bf16x8 af0[2], af1[2];
#pragma unroll
            for (int mt = 0; mt < 2; ++mt) {
                af0[mt] = *reinterpret_cast<const bf16x8*>(At + aoff + mt * 128);
                af1[mt] = *reinterpret_cast<const bf16x8*>(At + 4096 + aoff + mt * 128);
            }
            const unsigned short* Pb = &Ps[cur][0];
            bf16x8 bfr[4];
#pragma unroll
            for (int nt = 0; nt < 4; ++nt) bfr[nt] = ld_frag(Pb, nt * 16 + lrow, lg);
#pragma unroll
            for (int mt = 0; mt < 2; ++mt)
#pragma unroll
                for (int nt = 0; nt < 4; ++nt)
                    acc[mt][nt] = __builtin_amdgcn_mfma_f32_16x16x32_bf16(af0[mt], bfr[nt], acc[mt][nt], 0, 0, 0);
#pragma unroll
            for (int nt = 0; nt < 4; ++nt) bfr[nt] = ld_frag(Pb, nt * 16 + lrow, 4 + lg);
#pragma unroll
            for (int mt = 0; mt < 2; ++mt)
#pragma unroll
                for (int nt = 0; nt < 4; ++nt)
                    acc[mt][nt] = __builtin_amdgcn_mfma_f32_16x16x32_bf16(af1[mt], bfr[nt], acc[mt][nt], 0, 0, 0);

            __syncthreads();   // drains staging loads, then barrier
        }

        // epilogue -> C (B,T,DIM)
        const size_t base = (size_t)b * T_ * DIM + (size_t)h * HD;
#pragma unroll
        for (int mt = 0; mt < 2; ++mt) {
            int u = u0 + wv * 32 + mt * 16 + lg * 4;
            const float* tbp = tb + h * T_ + u;
            float t0v = tbp[0], t1v = tbp[1], t2v = tbp[2], t3v = tbp[3];
#pragma unroll
            for (int nt = 0; nt < 4; ++nt) {
                int d = nt * 16 + lrow;
                size_t p = base + (size_t)u * DIM + d;
                Cb[p]           = f2bf(acc[mt][nt][0] + t0v);
                Cb[p + DIM]     = f2bf(acc[mt][nt][1] + t1v);
                Cb[p + 2 * DIM] = f2bf(acc[mt][nt][2] + t2v);
                Cb[p + 3 * DIM] = f2bf(acc[mt][nt][3] + t3v);
            }
        }
    }
}

// ---------------------------------------------------------------------------
extern "C" void kernel_launch(void* const* d_in, const int* in_sizes, int n_in,
                              void* d_out, int out_size, void* d_ws, size_t ws_size,
                              hipStream_t stream) {
    (void)in_sizes; (void)n_in; (void)out_size; (void)ws_size;
    const float* x      = (const float*)d_in[0];
    const float* w_in   = (const float*)d_in[1];
    const float* b_in   = (const float*)d_in[2];
    const float* w_out  = (const float*)d_in[3];
    const float* b_out  = (const float*)d_in[4];
    const float* toep_w = (const float*)d_in[5];
    const float* toep_b = (const float*)d_in[6];

    char* ws = (char*)d_ws;
    unsigned short* XT    = (unsigned short*)(ws);                 // 32 MiB (B,T,DIM) bf16
    unsigned short* H1    = (unsigned short*)(ws + 33554432);      // 32 MiB (B,DIM,T) bf16
    unsigned short* Cbuf  = (unsigned short*)(ws + 67108864);      // 32 MiB (B,T,DIM) bf16
    unsigned short* Mfrag = (unsigned short*)(ws + 100663296);     // 8 MiB (H,32,8,128,8)
    unsigned short* WfI   = (unsigned short*)(ws + 109051904);     // 2 MiB (8,16,8,128,8)
    unsigned short* WfO   = (unsigned short*)(ws + 111149056);     // 2 MiB

    xpose_cast<<<dim3(T_ / 64, DIM / 64, B_), dim3(256), 0, stream>>>(x, XT);
    gen_mfrag<<<dim3(32, H_), dim3(256), 0, stream>>>(toep_w, Mfrag);
    gen_wfrag<<<dim3(16, 8), dim3(256), 0, stream>>>(w_in, WfI);
    gen_wfrag<<<dim3(16, 8), dim3(256), 0, stream>>>(w_out, WfO);
    gemm4_k<true><<<dim3(512), dim3(256), 0, stream>>>(WfI, XT, b_in, (void*)H1);
    conv4_k<<<dim3(1024), dim3(256), 0, stream>>>(H1, Mfrag, toep_b, Cbuf);
    gemm4_k<false><<<dim3(512), dim3(256), 0, stream>>>(WfO, Cbuf, b_out, d_out);
}

// Round 12
// 154.395 us; speedup vs baseline: 1.0730x; 1.0730x over previous
//
#include <hip/hip_runtime.h>
#include <hip/hip_bf16.h>
#include <stdint.h>

#define B_   8
#define DIM  1024
#define T_   2048
#define H_   16
#define HD   64

typedef __attribute__((ext_vector_type(8))) short bf16x8;
typedef __attribute__((ext_vector_type(4))) float f32x4;
typedef __attribute__((ext_vector_type(4))) unsigned short u16x4;

__device__ __forceinline__ unsigned short f2bf(float f) {
    union { float f; unsigned u; } v{f};
    unsigned r = v.u + 0x7fffu + ((v.u >> 16) & 1u);   // RNE
    return (unsigned short)(r >> 16);
}

// async 16B/lane global->LDS; lds dest must be wave-uniform base (HW adds lane*16)
__device__ __forceinline__ void gl_lds16(const unsigned short* g, unsigned short* l) {
    __builtin_amdgcn_global_load_lds(
        (const __attribute__((address_space(1))) void*)(const void*)g,
        (__attribute__((address_space(3))) void*)(void*)l,
        16, 0, 0);
}

// Read one 16B MFMA fragment from a swizzled [rows][64] bf16 LDS tile.
// Physical 16B-block = logical_colgroup ^ (row&7).
__device__ __forceinline__ bf16x8 ld_frag(const unsigned short* smem, int row, int cg) {
    return *reinterpret_cast<const bf16x8*>(smem + row * 64 + (((cg) ^ (row & 7)) << 3));
}

// ---------------------------------------------------------------------------
// Kernel 1: x (B,DIM,T) f32  ->  XT (B,T,DIM) bf16   (transpose + cast)
// ---------------------------------------------------------------------------
__global__ void xpose_cast(const float* __restrict__ x, unsigned short* __restrict__ xt) {
    __shared__ float tile[64][65];
    const int b = blockIdx.z;
    const int d0 = blockIdx.y * 64, t0 = blockIdx.x * 64;
    const int tid = threadIdx.x;
    const int c = tid & 63;
    const int r0 = tid >> 6;

    const float* xp = x + ((size_t)b * DIM + d0) * T_ + t0;
#pragma unroll
    for (int i = 0; i < 16; ++i) {
        int r = r0 + i * 4;                       // d offset
        tile[r][c] = xp[(size_t)r * T_ + c];
    }
    __syncthreads();
    unsigned short* op = xt + ((size_t)b * T_ + t0) * DIM + d0;
    const int ci = (tid & 15) * 4;                // d offset (4-wide)
    const int rr = tid >> 4;                      // t offset base 0..15
#pragma unroll
    for (int i = 0; i < 4; ++i) {
        int r = rr + i * 16;                      // t offset
        u16x4 v;
#pragma unroll
        for (int j = 0; j < 4; ++j) v[j] = f2bf(tile[ci + j][r]);
        *reinterpret_cast<u16x4*>(op + (size_t)r * DIM + ci) = v;
    }
}

// ---------------------------------------------------------------------------
// Kernel 2: cast w_in, w_out to bf16 (row-major, for LDS-staged gemm)
// ---------------------------------------------------------------------------
__global__ void cast_weights(const float* __restrict__ w_in, const float* __restrict__ w_out,
                             unsigned short* __restrict__ w_in_b, unsigned short* __restrict__ w_out_b) {
    int i = blockIdx.x * 256 + threadIdx.x;
    if (i < DIM * DIM) {
        w_in_b[i]  = f2bf(w_in[i]);
        w_out_b[i] = f2bf(w_out[i]);
    }
}

// ---------------------------------------------------------------------------
// Kernel 3: build diagonal M-tiles in MFMA *fragment* layout (f32 src):
// Mf[h][dg][cg][row][j] = w[h][ 64*(dg-1) + row - (cg*8+j) ]  (0 if lag<0)
// ---------------------------------------------------------------------------
__global__ void gen_mfrag(const float* __restrict__ tw, unsigned short* __restrict__ Mf) {
    const int h = blockIdx.y, dg = blockIdx.x;
    const int D = (dg - 1) * 64;
    const float* twh = tw + h * T_;
    unsigned short* out = Mf + (((size_t)h * 32 + dg) << 13);   // 8192 elems per (h,dg)
    for (int v = threadIdx.x; v < 1024; v += 256) {
        int cg = v >> 7, row = v & 127;
        bf16x8 w;
#pragma unroll
        for (int j = 0; j < 8; ++j) {
            int lag = D + row - (cg * 8 + j);
            w[j] = (lag >= 0) ? (short)f2bf(twh[lag]) : (short)0;
        }
        *reinterpret_cast<bf16x8*>(out + (size_t)v * 8) = w;
    }
}

// ---------------------------------------------------------------------------
// GEMM (R3-exact, proven): Out_b = W @ B_b + bias. 128x128 tile, BK=64,
// 4 waves (2x2 of 64x64), single-buffer A+B LDS, 2-barrier K-loop.
// 1-D grid + chunked XCD swizzle (each XCD owns one batch).
// ---------------------------------------------------------------------------
template <bool OUT_BF16>
__global__ void gemm_k(const unsigned short* __restrict__ Aw,   // (DIM,DIM) bf16
                       const unsigned short* __restrict__ Bm,   // (B,T,DIM) bf16
                       const float* __restrict__ bias,          // (DIM) f32
                       void* __restrict__ Out) {
    __shared__ __align__(16) unsigned short As[128 * 64];
    __shared__ __align__(16) unsigned short Bs[128 * 64];

    const int flat = blockIdx.x;                 // 1024 blocks
    const int wid  = (flat & 7) * 128 + (flat >> 3);
    const int nx   = wid & 15;
    const int my   = (wid >> 4) & 7;
    const int b    = wid >> 7;

    const int tid = threadIdx.x, lane = tid & 63, wv = tid >> 6;
    const int m0 = my * 128;
    const int n0 = nx * 128;
    const unsigned short* Bb = Bm + (size_t)b * T_ * DIM;

    const int wr = wv >> 1, wc = wv & 1;
    const int lrow = lane & 15, lg = lane >> 4;

    f32x4 acc[4][4] = {};

    for (int k0 = 0; k0 < DIM; k0 += 64) {
        __syncthreads();
#pragma unroll
        for (int it = 0; it < 4; ++it) {
            int ch = wv * 4 + it;
            int r  = ch * 8 + (lane >> 3);
            int g  = (lane & 7) ^ (lane >> 3);
            gl_lds16(Aw + (size_t)(m0 + r) * DIM + k0 + g * 8, As + ch * 512);
            gl_lds16(Bb + (size_t)(n0 + r) * DIM + k0 + g * 8, Bs + ch * 512);
        }
        __syncthreads();

#pragma unroll
        for (int kk = 0; kk < 2; ++kk) {
            bf16x8 af[4], bfr[4];
#pragma unroll
            for (int mt = 0; mt < 4; ++mt) af[mt]  = ld_frag(As, wr * 64 + mt * 16 + lrow, kk * 4 + lg);
#pragma unroll
            for (int nt = 0; nt < 4; ++nt) bfr[nt] = ld_frag(Bs, wc * 64 + nt * 16 + lrow, kk * 4 + lg);
#pragma unroll
            for (int mt = 0; mt < 4; ++mt)
#pragma unroll
                for (int nt = 0; nt < 4; ++nt)
                    acc[mt][nt] = __builtin_amdgcn_mfma_f32_16x16x32_bf16(af[mt], bfr[nt], acc[mt][nt], 0, 0, 0);
        }
    }

    const size_t ob = (size_t)b * DIM * T_;
#pragma unroll
    for (int mt = 0; mt < 4; ++mt) {
        int d = m0 + wr * 64 + mt * 16 + lg * 4;
#pragma unroll
        for (int nt = 0; nt < 4; ++nt) {
            int t = n0 + wc * 64 + nt * 16 + lrow;
#pragma unroll
            for (int r = 0; r < 4; ++r) {
                float v = acc[mt][nt][r] + bias[d + r];
                if constexpr (OUT_BF16)
                    ((unsigned short*)Out)[ob + (size_t)(d + r) * T_ + t] = f2bf(v);
                else
                    ((float*)Out)[ob + (size_t)(d + r) * T_ + t] = v;
            }
        }
    }
}

// ---------------------------------------------------------------------------
// Conv v7: conv4 with 2-wave (128-thread) blocks. Same grid (1024), same LDS
// (16 KB dbuf Ps), same swizzle/A-direct/balanced-triangle/h-major XCD chunk.
// Each wave owns 64u x 64d (acc[4][4]): per wave-K-step 32 MFMA vs 8 ds_read
// (was 16 vs 8) -> MFMA-bound ratio, occupancy preserved (8 blocks/CU cap).
// ---------------------------------------------------------------------------
__global__ __launch_bounds__(128)
void conv7_k(const unsigned short* __restrict__ H1,   // (B,DIM,T) bf16
             const unsigned short* __restrict__ Mf,   // (H,32,8,128,8) bf16
             const float* __restrict__ tb,            // (H,T) f32
             unsigned short* __restrict__ Cb) {       // (B,T,DIM) bf16
    __shared__ __align__(16) unsigned short Ps[2][64 * 64];

    const int flat = blockIdx.x;                 // 1024 blocks
    const int wid  = (flat & 7) * 128 + (flat >> 3);
    const int bx   = wid & 7;
    const int b    = (wid >> 3) & 7;
    const int h    = wid >> 6;

    const int tid = threadIdx.x, lane = tid & 63, wv = tid >> 6;   // wv in {0,1}
    const unsigned short* Hb = H1 + ((size_t)b * DIM + h * HD) * T_;
    const unsigned short* Ah = Mf + ((size_t)h * 32) * 8192;

    const int lrow = lane & 15, lg = lane >> 4;
    const int rsub = lane >> 3;
    const int g = (lane & 7) ^ rsub;

    // lane-constant part of the A-fragment offset (elems): cg=lg, row=wv*64+mt*16+lrow
    const int aoff = (lg * 128 + wv * 64 + lrow) * 8;

    auto PSTAGE = [&](int kt, int p) {
        const int t0 = kt * 64;
#pragma unroll
        for (int it = 0; it < 4; ++it) {
            int ch = wv * 4 + it;                 // 8 chunks of 8 rows
            int r  = ch * 8 + rsub;
            gl_lds16(Hb + (size_t)r * T_ + t0 + g * 8, &Ps[p][0] + ch * 512);
        }
    };

#pragma unroll
    for (int ph = 0; ph < 2; ++ph) {
        const int ut = ph ? bx : (T_ / 128 - 1 - bx);
        const int u0 = ut * 128;
        const int nk = 2 * ut + 2;
        f32x4 acc[4][4] = {};

        PSTAGE(0, 0);
        __syncthreads();

        for (int kt = 0; kt < nk; ++kt) {
            const int cur = kt & 1;
            if (kt + 1 < nk) PSTAGE(kt + 1, cur ^ 1);   // prefetch flies over compute

            // A fragments straight from L2 (fragment-layout Mf)
            const int dg = 2 * ut - kt + 1;
            const unsigned short* At = Ah + (size_t)dg * 8192;
            const unsigned short* Pb = &Ps[cur][0];

            // kk = 0
            {
                bf16x8 af[4], bfr[4];
#pragma unroll
                for (int mt = 0; mt < 4; ++mt)
                    af[mt] = *reinterpret_cast<const bf16x8*>(At + aoff + mt * 128);
#pragma unroll
                for (int nt = 0; nt < 4; ++nt) bfr[nt] = ld_frag(Pb, nt * 16 + lrow, lg);
#pragma unroll
                for (int mt = 0; mt < 4; ++mt)
#pragma unroll
                    for (int nt = 0; nt < 4; ++nt)
                        acc[mt][nt] = __builtin_amdgcn_mfma_f32_16x16x32_bf16(af[mt], bfr[nt], acc[mt][nt], 0, 0, 0);
            }
            // kk = 1
            {
                bf16x8 af[4], bfr[4];
#pragma unroll
                for (int mt = 0; mt < 4; ++mt)
                    af[mt] = *reinterpret_cast<const bf16x8*>(At + 4096 + aoff + mt * 128);
#pragma unroll
                for (int nt = 0; nt < 4; ++nt) bfr[nt] = ld_frag(Pb, nt * 16 + lrow, 4 + lg);
#pragma unroll
                for (int mt = 0; mt < 4; ++mt)
#pragma unroll
                    for (int nt = 0; nt < 4; ++nt)
                        acc[mt][nt] = __builtin_amdgcn_mfma_f32_16x16x32_bf16(af[mt], bfr[nt], acc[mt][nt], 0, 0, 0);
            }

            __syncthreads();   // drains staging loads, then barrier
        }

        // epilogue -> C (B,T,DIM)
        const size_t base = (size_t)b * T_ * DIM + (size_t)h * HD;
#pragma unroll
        for (int mt = 0; mt < 4; ++mt) {
            int u = u0 + wv * 64 + mt * 16 + lg * 4;
            const float* tbp = tb + h * T_ + u;
            float t0v = tbp[0], t1v = tbp[1], t2v = tbp[2], t3v = tbp[3];
#pragma unroll
            for (int nt = 0; nt < 4; ++nt) {
                int d = nt * 16 + lrow;
                size_t p = base + (size_t)u * DIM + d;
                Cb[p]           = f2bf(acc[mt][nt][0] + t0v);
                Cb[p + DIM]     = f2bf(acc[mt][nt][1] + t1v);
                Cb[p + 2 * DIM] = f2bf(acc[mt][nt][2] + t2v);
                Cb[p + 3 * DIM] = f2bf(acc[mt][nt][3] + t3v);
            }
        }
    }
}

// ---------------------------------------------------------------------------
extern "C" void kernel_launch(void* const* d_in, const int* in_sizes, int n_in,
                              void* d_out, int out_size, void* d_ws, size_t ws_size,
                              hipStream_t stream) {
    (void)in_sizes; (void)n_in; (void)out_size; (void)ws_size;
    const float* x      = (const float*)d_in[0];
    const float* w_in   = (const float*)d_in[1];
    const float* b_in   = (const float*)d_in[2];
    const float* w_out  = (const float*)d_in[3];
    const float* b_out  = (const float*)d_in[4];
    const float* toep_w = (const float*)d_in[5];
    const float* toep_b = (const float*)d_in[6];

    char* ws = (char*)d_ws;
    unsigned short* XT    = (unsigned short*)(ws);                 // 32 MiB (B,T,DIM) bf16
    unsigned short* H1    = (unsigned short*)(ws + 33554432);      // 32 MiB (B,DIM,T) bf16
    unsigned short* Cbuf  = (unsigned short*)(ws + 67108864);      // 32 MiB (B,T,DIM) bf16
    unsigned short* winb  = (unsigned short*)(ws + 100663296);     // 2 MiB
    unsigned short* woutb = (unsigned short*)(ws + 102760448);     // 2 MiB
    unsigned short* Mfrag = (unsigned short*)(ws + 104857600);     // 8 MiB (H,32,8,128,8)

    xpose_cast<<<dim3(T_ / 64, DIM / 64, B_), dim3(256), 0, stream>>>(x, XT);
    cast_weights<<<dim3((DIM * DIM) / 256), dim3(256), 0, stream>>>(w_in, w_out, winb, woutb);
    gen_mfrag<<<dim3(32, H_), dim3(256), 0, stream>>>(toep_w, Mfrag);
    gemm_k<true><<<dim3(1024), dim3(256), 0, stream>>>(winb, XT, b_in, (void*)H1);
    conv7_k<<<dim3(1024), dim3(128), 0, stream>>>(H1, Mfrag, toep_b, Cbuf);
    gemm_k<false><<<dim3(1024), dim3(256), 0, stream>>>(woutb, Cbuf, b_out, d_out);
}